// Round 6
// baseline (785.063 us; speedup 1.0000x reference)
//
#include <hip/hip_runtime.h>
#include <math.h>

// Problem constants: b=16, c=64, h=w=256, pool=8, wh=ww=32, n=64, dim_k=64.
// out[b,c, nr*32+i, nc*32+j] = sum_m dist[b, nr*8+nc, m] * x[b,c, mr*32+i, mc*32+j]

// Native clang vector type — accepted by __builtin_nontemporal_store.
typedef float nfloat4 __attribute__((ext_vector_type(4)));

// ---------------- Kernel 1: adaptive avg pool → yT[b][c][n] ----------------
// HBM-bound at ~80% of peak — left alone.
__global__ __launch_bounds__(256) void pool_kernel(const float* __restrict__ x,
                                                   float* __restrict__ yT)
{
    int bc = blockIdx.x;            // b*64 + c
    int b  = bc >> 6, c = bc & 63;
    const float4* plane = (const float4*)(x + (size_t)bc * 65536);
    int t    = threadIdx.x;
    int col4 = t & 63;              // float4 column within a row (0..63)
    int q    = t >> 6;              // wave id → row offset within 4-row slab

    float acc[8];
#pragma unroll
    for (int wr = 0; wr < 8; ++wr) acc[wr] = 0.f;

#pragma unroll
    for (int wr = 0; wr < 8; ++wr) {
#pragma unroll
        for (int it = 0; it < 8; ++it) {
            int row = wr * 32 + it * 4 + q;
            float4 v = plane[row * 64 + col4];
            acc[wr] += v.x + v.y + v.z + v.w;
        }
    }

    __shared__ float red[8][264];   // pad 264 (%32==8) — write phase conflict-free
#pragma unroll
    for (int wr = 0; wr < 8; ++wr) red[wr][t] = acc[wr];
    __syncthreads();

    if (t < 64) {
        int wr = t >> 3, wc = t & 7;   // window n = t
        float s = 0.f;
#pragma unroll
        for (int qq = 0; qq < 4; ++qq)
#pragma unroll
            for (int ss = 0; ss < 8; ++ss)
                s += red[wr][qq * 64 + wc * 8 + ss];
        yT[b * 4096 + c * 64 + t] = s * (1.0f / 1024.0f);
    }
}

// -------- Kernel 2: q,k,S,softmax → distN[b][n][m] (natural layout) -------
// Round-6 change: the combine kernel now wants dist[b][n][m] (row-major in m).
// Each thread already holds s[i] = dist[n=ng*16+i][m=lane] in registers, so
// we write that layout DIRECTLY (coalesced: lane = m contiguous) and delete
// the sT transpose staging entirely.
#define ST 68   // padded stride: float4-aligned, breaks power-of-2 banking
__global__ __launch_bounds__(256) void attn_kernel(const float* __restrict__ yT,
                                                   const float* __restrict__ Wq,
                                                   const float* __restrict__ Wk,
                                                   float* __restrict__ distN)
{
    __shared__ float ylT[64 * ST];  // [c][n]
    __shared__ float wqT[64 * ST];  // [c][d]
    __shared__ float wkT[64 * ST];  // [c][d]
    __shared__ float qlT[64 * ST];  // [d][n]
    __shared__ float klT[64 * ST];  // [d][m]
    int b = blockIdx.x, t = threadIdx.x;

#pragma unroll
    for (int o = 0; o < 16; ++o) {
        int idx = o * 256 + t;
        int r = idx >> 6, cl = idx & 63;    // r wave-uniform, cl = lane
        ylT[r * ST + cl] = yT[b * 4096 + idx];
        wqT[cl * ST + r] = Wq[idx];
        wkT[cl * ST + r] = Wk[idx];
    }
    __syncthreads();

    int lane = t & 63, ng = t >> 6;   // ng wave-uniform

    // Phase 2: q[n][d], k[n][d] for d=lane, n = ng*16..+15
    float qa[16], ka[16];
#pragma unroll
    for (int i = 0; i < 16; ++i) { qa[i] = 0.f; ka[i] = 0.f; }
    for (int c = 0; c < 64; ++c) {
        float wq = wqT[c * ST + lane];          // unit-stride across lanes
        float wk = wkT[c * ST + lane];
        const float4* yr = (const float4*)(ylT + c * ST + ng * 16);  // broadcast
        float4 y0 = yr[0], y1 = yr[1], y2 = yr[2], y3 = yr[3];
        qa[0]  += y0.x * wq; qa[1]  += y0.y * wq; qa[2]  += y0.z * wq; qa[3]  += y0.w * wq;
        qa[4]  += y1.x * wq; qa[5]  += y1.y * wq; qa[6]  += y1.z * wq; qa[7]  += y1.w * wq;
        qa[8]  += y2.x * wq; qa[9]  += y2.y * wq; qa[10] += y2.z * wq; qa[11] += y2.w * wq;
        qa[12] += y3.x * wq; qa[13] += y3.y * wq; qa[14] += y3.z * wq; qa[15] += y3.w * wq;
        ka[0]  += y0.x * wk; ka[1]  += y0.y * wk; ka[2]  += y0.z * wk; ka[3]  += y0.w * wk;
        ka[4]  += y1.x * wk; ka[5]  += y1.y * wk; ka[6]  += y1.z * wk; ka[7]  += y1.w * wk;
        ka[8]  += y2.x * wk; ka[9]  += y2.y * wk; ka[10] += y2.z * wk; ka[11] += y2.w * wk;
        ka[12] += y3.x * wk; ka[13] += y3.y * wk; ka[14] += y3.z * wk; ka[15] += y3.w * wk;
    }
    {
        float4* qd = (float4*)(qlT + lane * ST + ng * 16);
        float4* kd = (float4*)(klT + lane * ST + ng * 16);
        qd[0] = make_float4(qa[0],  qa[1],  qa[2],  qa[3]);
        qd[1] = make_float4(qa[4],  qa[5],  qa[6],  qa[7]);
        qd[2] = make_float4(qa[8],  qa[9],  qa[10], qa[11]);
        qd[3] = make_float4(qa[12], qa[13], qa[14], qa[15]);
        kd[0] = make_float4(ka[0],  ka[1],  ka[2],  ka[3]);
        kd[1] = make_float4(ka[4],  ka[5],  ka[6],  ka[7]);
        kd[2] = make_float4(ka[8],  ka[9],  ka[10], ka[11]);
        kd[3] = make_float4(ka[12], ka[13], ka[14], ka[15]);
    }
    __syncthreads();

    // Phase 3: S[n][m] for m=lane, n = ng*16..+15
    float s[16];
#pragma unroll
    for (int i = 0; i < 16; ++i) s[i] = 0.f;
    for (int d = 0; d < 64; ++d) {
        float kv = klT[d * ST + lane];          // unit-stride
        const float4* qr = (const float4*)(qlT + d * ST + ng * 16);  // broadcast
        float4 q0 = qr[0], q1 = qr[1], q2 = qr[2], q3 = qr[3];
        s[0]  += q0.x * kv; s[1]  += q0.y * kv; s[2]  += q0.z * kv; s[3]  += q0.w * kv;
        s[4]  += q1.x * kv; s[5]  += q1.y * kv; s[6]  += q1.z * kv; s[7]  += q1.w * kv;
        s[8]  += q2.x * kv; s[9]  += q2.y * kv; s[10] += q2.z * kv; s[11] += q2.w * kv;
        s[12] += q3.x * kv; s[13] += q3.y * kv; s[14] += q3.z * kv; s[15] += q3.w * kv;
    }
    const float scale = 0.125f;   // 1/sqrt(64)
#pragma unroll
    for (int i = 0; i < 16; ++i) {
        float v = s[i] * scale;
        float mx = v;
        mx = fmaxf(mx, __shfl_xor(mx, 1));
        mx = fmaxf(mx, __shfl_xor(mx, 2));
        mx = fmaxf(mx, __shfl_xor(mx, 4));
        mx = fmaxf(mx, __shfl_xor(mx, 8));
        mx = fmaxf(mx, __shfl_xor(mx, 16));
        mx = fmaxf(mx, __shfl_xor(mx, 32));
        float e = expf(v - mx);
        float sm = e;
        sm += __shfl_xor(sm, 1);
        sm += __shfl_xor(sm, 2);
        sm += __shfl_xor(sm, 4);
        sm += __shfl_xor(sm, 8);
        sm += __shfl_xor(sm, 16);
        sm += __shfl_xor(sm, 32);
        s[i] = e / sm;            // dist[n = ng*16+i][m = lane]
    }
    // Direct coalesced write of dist[b][n][m]: lane = m contiguous.
#pragma unroll
    for (int i = 0; i < 16; ++i)
        distN[b * 4096 + (ng * 16 + i) * 64 + lane] = s[i];
}

// ------------- Kernel 3: out = dist-weighted window combine --------------
// Round-6 rewrite (post-mortem of rounds 4/5):
//   R4: D in LDS → 192 ds_read_b128/thread, LDS-issue-bound (~123 µs pipe,
//       1.7e7 bank conflicts).  R5: D per-lane VMEM → latency-bound (167 µs).
// New structure: thread owns ONE within-window pixel (i,j), computes ALL 64
// window outputs for it.
//   * acc[n] += D[n][m] * xv[m]: D index depends only on blockIdx/loop
//     counters → WAVE-UNIFORM → s_load through the scalar cache (16 KB per
//     batch, fully cached). FMA is v_fmac_f32 v,s,v. Zero D vector traffic.
//   * Each x element read by exactly one thread → no LDS at all, no syncs.
//   * Per m-chunk: 8 coalesced global loads then 512 FMAs — latency hides.
//   * Reversed plane order keeps x L3-resident (R5 counters: FETCH 132 MB,
//     half of x); nontemporal scalar stores keep out from evicting x.
__global__ __launch_bounds__(256, 4) void combine_kernel(const float* __restrict__ x,
                                                         const float* __restrict__ distN,
                                                         float* __restrict__ out)
{
    int blk = blockIdx.x;
    int rg  = blk & 3;              // i-row group (8 rows each)
    int bc  = 1023 - (blk >> 2);    // REVERSED plane order (L3 LRU-friendly)
    int b   = bc >> 6;
    const float* plane  = x   + (size_t)bc * 65536;
    float*       oplane = out + (size_t)bc * 65536;
    const float* D      = distN + b * 4096;   // [n][m]

    int t = threadIdx.x;
    int j = t & 31;                 // within-window column
    int i = rg * 8 + (t >> 5);      // within-window row

    float acc[64];
#pragma unroll
    for (int n = 0; n < 64; ++n) acc[n] = 0.f;

    for (int mb = 0; mb < 8; ++mb) {          // m window-row chunk (mr = mb)
        const float* xrow = plane + (mb * 32 + i) * 256 + j;
        float xv[8];
#pragma unroll
        for (int mm = 0; mm < 8; ++mm)        // m = mb*8 + mm (mc = mm)
            xv[mm] = xrow[mm * 32];
        const float* Db = D + mb * 8;         // uniform base
#pragma unroll
        for (int n = 0; n < 64; ++n) {
#pragma unroll
            for (int mm = 0; mm < 8; ++mm)
                acc[n] = fmaf(Db[n * 64 + mm], xv[mm], acc[n]);
        }
    }

    float* obase = oplane + i * 256 + j;
#pragma unroll
    for (int n = 0; n < 64; ++n)
        __builtin_nontemporal_store(acc[n], obase + (n >> 3) * 8192 + (n & 7) * 32);
}

extern "C" void kernel_launch(void* const* d_in, const int* in_sizes, int n_in,
                              void* d_out, int out_size, void* d_ws, size_t ws_size,
                              hipStream_t stream)
{
    const float* x  = (const float*)d_in[0];   // (16, 64, 256, 256)
    const float* Wq = (const float*)d_in[1];   // (64, 64)
    const float* Wk = (const float*)d_in[2];   // (64, 64)
    float* out = (float*)d_out;                // (16, 64, 256, 256)

    float* y_ws  = (float*)d_ws;               // 65536 floats: yT[b][c][n]
    float* distN = y_ws + 65536;               // 65536 floats: distN[b][n][m]

    pool_kernel   <<<1024, 256, 0, stream>>>(x, y_ws);
    attn_kernel   <<<16,   256, 0, stream>>>(y_ws, Wq, Wk, distN);
    combine_kernel<<<4096, 256, 0, stream>>>(x, distN, out);
}

// Round 7
// 552.461 us; speedup vs baseline: 1.4210x; 1.4210x over previous
//
#include <hip/hip_runtime.h>
#include <math.h>

// Problem constants: b=16, c=64, h=w=256, pool=8, wh=ww=32, n=64, dim_k=64.
// out[b,c, nr*32+i, nc*32+j] = sum_m dist[b, nr*8+nc, m] * x[b,c, mr*32+i, mc*32+j]

// ---------------- Kernel 1: adaptive avg pool → yT[b][c][n] ----------------
// HBM-bound at ~80% of peak — left alone.
__global__ __launch_bounds__(256) void pool_kernel(const float* __restrict__ x,
                                                   float* __restrict__ yT)
{
    int bc = blockIdx.x;            // b*64 + c
    int b  = bc >> 6, c = bc & 63;
    const float4* plane = (const float4*)(x + (size_t)bc * 65536);
    int t    = threadIdx.x;
    int col4 = t & 63;              // float4 column within a row (0..63)
    int q    = t >> 6;              // wave id → row offset within 4-row slab

    float acc[8];
#pragma unroll
    for (int wr = 0; wr < 8; ++wr) acc[wr] = 0.f;

#pragma unroll
    for (int wr = 0; wr < 8; ++wr) {
#pragma unroll
        for (int it = 0; it < 8; ++it) {
            int row = wr * 32 + it * 4 + q;
            float4 v = plane[row * 64 + col4];
            acc[wr] += v.x + v.y + v.z + v.w;
        }
    }

    __shared__ float red[8][264];   // pad 264 (%32==8) — write phase conflict-free
#pragma unroll
    for (int wr = 0; wr < 8; ++wr) red[wr][t] = acc[wr];
    __syncthreads();

    if (t < 64) {
        int wr = t >> 3, wc = t & 7;   // window n = t
        float s = 0.f;
#pragma unroll
        for (int qq = 0; qq < 4; ++qq)
#pragma unroll
            for (int ss = 0; ss < 8; ++ss)
                s += red[wr][qq * 64 + wc * 8 + ss];
        yT[b * 4096 + c * 64 + t] = s * (1.0f / 1024.0f);
    }
}

// -------- Kernel 2: q,k,S,softmax → distN[b][n][m] (natural layout) -------
// UNCHANGED from Round 6 (verified correct; ~10 µs).
#define ST 68   // padded stride: float4-aligned, breaks power-of-2 banking
__global__ __launch_bounds__(256) void attn_kernel(const float* __restrict__ yT,
                                                   const float* __restrict__ Wq,
                                                   const float* __restrict__ Wk,
                                                   float* __restrict__ distN)
{
    __shared__ float ylT[64 * ST];  // [c][n]
    __shared__ float wqT[64 * ST];  // [c][d]
    __shared__ float wkT[64 * ST];  // [c][d]
    __shared__ float qlT[64 * ST];  // [d][n]
    __shared__ float klT[64 * ST];  // [d][m]
    int b = blockIdx.x, t = threadIdx.x;

#pragma unroll
    for (int o = 0; o < 16; ++o) {
        int idx = o * 256 + t;
        int r = idx >> 6, cl = idx & 63;    // r wave-uniform, cl = lane
        ylT[r * ST + cl] = yT[b * 4096 + idx];
        wqT[cl * ST + r] = Wq[idx];
        wkT[cl * ST + r] = Wk[idx];
    }
    __syncthreads();

    int lane = t & 63, ng = t >> 6;   // ng wave-uniform

    // Phase 2: q[n][d], k[n][d] for d=lane, n = ng*16..+15
    float qa[16], ka[16];
#pragma unroll
    for (int i = 0; i < 16; ++i) { qa[i] = 0.f; ka[i] = 0.f; }
    for (int c = 0; c < 64; ++c) {
        float wq = wqT[c * ST + lane];          // unit-stride across lanes
        float wk = wkT[c * ST + lane];
        const float4* yr = (const float4*)(ylT + c * ST + ng * 16);  // broadcast
        float4 y0 = yr[0], y1 = yr[1], y2 = yr[2], y3 = yr[3];
        qa[0]  += y0.x * wq; qa[1]  += y0.y * wq; qa[2]  += y0.z * wq; qa[3]  += y0.w * wq;
        qa[4]  += y1.x * wq; qa[5]  += y1.y * wq; qa[6]  += y1.z * wq; qa[7]  += y1.w * wq;
        qa[8]  += y2.x * wq; qa[9]  += y2.y * wq; qa[10] += y2.z * wq; qa[11] += y2.w * wq;
        qa[12] += y3.x * wq; qa[13] += y3.y * wq; qa[14] += y3.z * wq; qa[15] += y3.w * wq;
        ka[0]  += y0.x * wk; ka[1]  += y0.y * wk; ka[2]  += y0.z * wk; ka[3]  += y0.w * wk;
        ka[4]  += y1.x * wk; ka[5]  += y1.y * wk; ka[6]  += y1.z * wk; ka[7]  += y1.w * wk;
        ka[8]  += y2.x * wk; ka[9]  += y2.y * wk; ka[10] += y2.z * wk; ka[11] += y2.w * wk;
        ka[12] += y3.x * wk; ka[13] += y3.y * wk; ka[14] += y3.z * wk; ka[15] += y3.w * wk;
    }
    {
        float4* qd = (float4*)(qlT + lane * ST + ng * 16);
        float4* kd = (float4*)(klT + lane * ST + ng * 16);
        qd[0] = make_float4(qa[0],  qa[1],  qa[2],  qa[3]);
        qd[1] = make_float4(qa[4],  qa[5],  qa[6],  qa[7]);
        qd[2] = make_float4(qa[8],  qa[9],  qa[10], qa[11]);
        qd[3] = make_float4(qa[12], qa[13], qa[14], qa[15]);
        kd[0] = make_float4(ka[0],  ka[1],  ka[2],  ka[3]);
        kd[1] = make_float4(ka[4],  ka[5],  ka[6],  ka[7]);
        kd[2] = make_float4(ka[8],  ka[9],  ka[10], ka[11]);
        kd[3] = make_float4(ka[12], ka[13], ka[14], ka[15]);
    }
    __syncthreads();

    // Phase 3: S[n][m] for m=lane, n = ng*16..+15
    float s[16];
#pragma unroll
    for (int i = 0; i < 16; ++i) s[i] = 0.f;
    for (int d = 0; d < 64; ++d) {
        float kv = klT[d * ST + lane];          // unit-stride
        const float4* qr = (const float4*)(qlT + d * ST + ng * 16);  // broadcast
        float4 q0 = qr[0], q1 = qr[1], q2 = qr[2], q3 = qr[3];
        s[0]  += q0.x * kv; s[1]  += q0.y * kv; s[2]  += q0.z * kv; s[3]  += q0.w * kv;
        s[4]  += q1.x * kv; s[5]  += q1.y * kv; s[6]  += q1.z * kv; s[7]  += q1.w * kv;
        s[8]  += q2.x * kv; s[9]  += q2.y * kv; s[10] += q2.z * kv; s[11] += q2.w * kv;
        s[12] += q3.x * kv; s[13] += q3.y * kv; s[14] += q3.z * kv; s[15] += q3.w * kv;
    }
    const float scale = 0.125f;   // 1/sqrt(64)
#pragma unroll
    for (int i = 0; i < 16; ++i) {
        float v = s[i] * scale;
        float mx = v;
        mx = fmaxf(mx, __shfl_xor(mx, 1));
        mx = fmaxf(mx, __shfl_xor(mx, 2));
        mx = fmaxf(mx, __shfl_xor(mx, 4));
        mx = fmaxf(mx, __shfl_xor(mx, 8));
        mx = fmaxf(mx, __shfl_xor(mx, 16));
        mx = fmaxf(mx, __shfl_xor(mx, 32));
        float e = expf(v - mx);
        float sm = e;
        sm += __shfl_xor(sm, 1);
        sm += __shfl_xor(sm, 2);
        sm += __shfl_xor(sm, 4);
        sm += __shfl_xor(sm, 8);
        sm += __shfl_xor(sm, 16);
        sm += __shfl_xor(sm, 32);
        s[i] = e / sm;            // dist[n = ng*16+i][m = lane]
    }
    // Direct coalesced write of dist[b][n][m]: lane = m contiguous.
#pragma unroll
    for (int i = 0; i < 16; ++i)
        distN[b * 4096 + (ng * 16 + i) * 64 + lane] = s[i];
}

// ------------- Kernel 3: out = dist-weighted window combine --------------
// Round-7 rewrite. R6 post-mortem: acc[64] went to SCRATCH (VGPR=52 proves
// it) because the 64-iter n-loop wasn't fully unrolled → runtime indexing.
// New structure eliminates the accumulator array entirely:
//   * Load all 64 x-window values for this thread's pixel FIRST (xv[64],
//     statically indexed in a constant-trip unrolled loop → 64 VGPRs).
//   * n-loop stays ROLLED: per n, D[n][0..63] is 64 contiguous floats at a
//     wave-uniform address (read-only, __restrict__) → s_load dwordx16;
//     64 v_fmac v,s,v into 4 scalar partials (chain-broken); one
//     nontemporal store. No acc array, no LDS, no __syncthreads.
//   * Reversed plane order keeps x half-L3-resident (R5/R6 counters:
//     FETCH 133 MB ≈ x/2); nontemporal stores keep out from evicting x.
__global__ __launch_bounds__(256, 4) void combine_kernel(const float* __restrict__ x,
                                                         const float* __restrict__ distN,
                                                         float* __restrict__ out)
{
    int blk = blockIdx.x;
    int rg  = blk & 3;              // i-row group (8 rows each)
    int bc  = 1023 - (blk >> 2);    // REVERSED plane order (L3 LRU-friendly)
    int b   = bc >> 6;
    const float* plane  = x   + (size_t)bc * 65536;
    float*       oplane = out + (size_t)bc * 65536;
    const float* D      = distN + b * 4096;   // [n][m]

    int t = threadIdx.x;
    int j = t & 31;                 // within-window column
    int i = rg * 8 + (t >> 5);      // within-window row

    // All 64 window-values of this pixel: xv[m = mb*8+mm] = x[mb*32+i][mm*32+j]
    float xv[64];
#pragma unroll
    for (int mb = 0; mb < 8; ++mb) {
        const float* xrow = plane + (mb * 32 + i) * 256 + j;
#pragma unroll
        for (int mm = 0; mm < 8; ++mm)
            xv[mb * 8 + mm] = xrow[mm * 32];
    }

    float* obase = oplane + i * 256 + j;
    for (int n = 0; n < 64; ++n) {            // rolled — tiny body, no arrays
        const float* Dn = D + n * 64;         // wave-uniform → scalar loads
        float p0 = 0.f, p1 = 0.f, p2 = 0.f, p3 = 0.f;
#pragma unroll
        for (int m = 0; m < 64; m += 4) {     // xv indices compile-time const
            p0 = fmaf(Dn[m],     xv[m],     p0);
            p1 = fmaf(Dn[m + 1], xv[m + 1], p1);
            p2 = fmaf(Dn[m + 2], xv[m + 2], p2);
            p3 = fmaf(Dn[m + 3], xv[m + 3], p3);
        }
        __builtin_nontemporal_store((p0 + p1) + (p2 + p3),
                                    obase + (n >> 3) * 8192 + (n & 7) * 32);
    }
}

extern "C" void kernel_launch(void* const* d_in, const int* in_sizes, int n_in,
                              void* d_out, int out_size, void* d_ws, size_t ws_size,
                              hipStream_t stream)
{
    const float* x  = (const float*)d_in[0];   // (16, 64, 256, 256)
    const float* Wq = (const float*)d_in[1];   // (64, 64)
    const float* Wk = (const float*)d_in[2];   // (64, 64)
    float* out = (float*)d_out;                // (16, 64, 256, 256)

    float* y_ws  = (float*)d_ws;               // 65536 floats: yT[b][c][n]
    float* distN = y_ws + 65536;               // 65536 floats: distN[b][n][m]

    pool_kernel   <<<1024, 256, 0, stream>>>(x, y_ws);
    attn_kernel   <<<16,   256, 0, stream>>>(y_ws, Wq, Wk, distN);
    combine_kernel<<<4096, 256, 0, stream>>>(x, distN, out);
}